// Round 3
// baseline (7421.699 us; speedup 1.0000x reference)
//
#include <hip/hip_runtime.h>

#define TM1     127
#define NE      128
#define STRIDEF 132          // row stride in floats (16B-aligned rows)
#define S4      33           // row stride in float4
#define NT      1024
#define NB      256
#define ROUNDS  4

#if __has_builtin(__builtin_amdgcn_exp2f)
#define EXP2(x) __builtin_amdgcn_exp2f(x)
#else
#define EXP2(x) exp2f(x)
#endif
#define RCP(x) __builtin_amdgcn_rcpf(x)

__device__ __forceinline__ float fast_sig(float x) {
    return RCP(1.0f + __expf(-x));
}
__device__ __forceinline__ float fast_tanh(float x) {
    float e = __expf(2.0f * x);             // inf -> tanh=1 (correct)
    return 1.0f - 2.0f * RCP(e + 1.0f);
}

// 2*log2(e): preX2/u2s pre-scaled so tanh costs add+exp2+add+rcp+fma only
#define K2 2.885390081777927f

__global__ __launch_bounds__(NT, 4)
void decoder_kernel(const float* __restrict__ Xg,     // (B,127,128)
                    const float* __restrict__ yprev,  // (B,127)
                    const float* __restrict__ W1,     // (384,128): [d;c;x]
                    const float* __restrict__ b1,
                    const float* __restrict__ W2,     // (128)
                    const float* __restrict__ b2v,
                    const float* __restrict__ Wfc,    // (129)
                    const float* __restrict__ bfcv,
                    const float* __restrict__ Wx,     // (512)
                    const float* __restrict__ Wh,     // (128,512)
                    const float* __restrict__ blv,    // (512)
                    const float* __restrict__ Wf,     // (256)
                    const float* __restrict__ bfv,
                    float* __restrict__ out)          // (B)
{
    __shared__ __align__(16) float Xs   [128 * STRIDEF];
    __shared__ __align__(16) float preX2[128 * STRIDEF];  // K2*(b1 + X@W1x)
    __shared__ __align__(16) float sdc  [256];            // d | c
    __shared__ __align__(16) float u2s  [128];            // K2*u
    __shared__ __align__(16) float w2m2 [128];            // -2*W2
    __shared__ __align__(16) float zs   [512];            // d@Wh partials
    __shared__ __align__(16) float swave[16];
    __shared__ float XWfcs[128];
    __shared__ float betas[128];
    __shared__ float ys   [TM1];
    __shared__ float wxbl [1024];                          // Wx(512) | bl(512)
    __shared__ float scrE [128];

    const int tid = (int)threadIdx.x;
    const int e_u = tid >> 3, o  = tid & 7;   // u-phase: output e_u, 8-way k-split
    const int jz  = tid >> 1, sz = tid & 1;   // z-phase: output jz, 2-way k-split
    const int tp  = tid >> 3, p  = tid & 7;   // tanh phase: row tp, 8-way e-split
    const int e_s = tid & 127, rg = tid >> 7; // staging / preX
    const int wv  = tid >> 6;

    // ---- persistent weights: 32 + 64 = 96 VGPRs (fits the 128 budget) ----
    float w1r[32];                             // W1dc[k][e_u], k in o's 32-slice (rotated)
    #pragma unroll
    for (int i4 = 0; i4 < 8; ++i4) {
        const int j4 = o * 8 + ((i4 + o) & 7);
        #pragma unroll
        for (int m = 0; m < 4; ++m)
            w1r[i4 * 4 + m] = W1[(j4 * 4 + m) * NE + e_u];
    }
    float whr[64];                             // Wh[k][jz], k in sz's 64-slice
    #pragma unroll
    for (int i4 = 0; i4 < 16; ++i4) {
        const int j4 = sz * 16 + i4;
        #pragma unroll
        for (int m = 0; m < 4; ++m)
            whr[i4 * 4 + m] = Wh[(j4 * 4 + m) * 512 + jz];
    }
    // tanh-phase accumulator init: b2/8 + sum of my W2 slice (algebraic fold)
    float pinit = b2v[0] * 0.125f;
    #pragma unroll
    for (int i = 0; i < 16; ++i) pinit += W2[p * 16 + i];

    const float wfcy  = Wfc[NE];
    const float bfc_r = bfcv[0];
    const float bf_r  = bfv[0];

    if (tid < 128) w2m2[tid] = -2.0f * W2[tid];
    wxbl[tid] = (tid < 512) ? Wx[tid] : blv[tid - 512];

    const float4* sdc4 = (const float4*)sdc;
    const float4* pX4  = (const float4*)preX2;
    const float4* u24  = (const float4*)u2s;
    const float4* w24  = (const float4*)w2m2;
    const float4* Xs4  = (const float4*)Xs;
    const float4* sw4  = (const float4*)swave;

    for (int r = 0; r < ROUNDS; ++r) {
        const int b = (int)blockIdx.x + r * NB;
        const float* __restrict__ Xb = Xg + (size_t)b * (TM1 * NE);

        if (tid < 128) { float x00 = Xb[0]; sdc[tid] = x00; sdc[128 + tid] = x00; }
        if (tid < TM1) ys[tid] = yprev[(size_t)b * TM1 + tid];
        #pragma unroll
        for (int j = 0; j < 16; ++j) {                 // coalesced; row 127 zeroed
            const int rr = rg * 16 + j;
            Xs[rr * STRIDEF + e_s] = (rr < TM1) ? Xb[rr * NE + e_s] : 0.0f;
        }
        __syncthreads();

        // ---- preX2[t'][e] = K2*(b1 + X[t']@W1x); Xs reads are wave-uniform b128 ----
        {
            float acc[16];
            const float b1r = b1[e_s];
            #pragma unroll
            for (int j = 0; j < 16; ++j) acc[j] = b1r;
            for (int k4 = 0; k4 < 32; ++k4) {
                const float wa = W1[(256 + k4 * 4 + 0) * NE + e_s];
                const float wb = W1[(256 + k4 * 4 + 1) * NE + e_s];
                const float wc = W1[(256 + k4 * 4 + 2) * NE + e_s];
                const float wd = W1[(256 + k4 * 4 + 3) * NE + e_s];
                #pragma unroll
                for (int j = 0; j < 16; ++j) {
                    const float4 x = Xs4[(rg * 16 + j) * S4 + k4];
                    acc[j] = fmaf(wa, x.x, fmaf(wb, x.y, fmaf(wc, x.z, fmaf(wd, x.w, acc[j]))));
                }
            }
            #pragma unroll
            for (int j = 0; j < 16; ++j)
                preX2[(rg * 16 + j) * STRIDEF + e_s] = K2 * acc[j];
        }
        // ---- XWfc[t'] = X[t'].Wfc[:128]  (per-step ctx eliminated) ----
        {
            float pw = 0.0f;
            #pragma unroll
            for (int c4 = 0; c4 < 4; ++c4) {
                const float4 x = Xs4[tp * S4 + p * 4 + c4];
                pw = fmaf(x.x, Wfc[p * 16 + c4 * 4 + 0], pw);
                pw = fmaf(x.y, Wfc[p * 16 + c4 * 4 + 1], pw);
                pw = fmaf(x.z, Wfc[p * 16 + c4 * 4 + 2], pw);
                pw = fmaf(x.w, Wfc[p * 16 + c4 * 4 + 3], pw);
            }
            pw += __shfl_xor(pw, 1);
            pw += __shfl_xor(pw, 2);
            pw += __shfl_xor(pw, 4);
            if (p == 0) XWfcs[tp] = pw;                // row 127 -> 0 (Xs zeroed)
        }
        __syncthreads();

        for (int t = 0; t < TM1; ++t) {
            // ==== A: u partials (8-way) + z partials (2-way), from sdc ====
            float pa = 0.0f;
            #pragma unroll
            for (int i4 = 0; i4 < 8; ++i4) {           // rotated: conflict-free
                const float4 v = sdc4[o * 8 + ((i4 + o) & 7)];
                const int ib = i4 * 4;
                pa = fmaf(w1r[ib + 0], v.x, pa); pa = fmaf(w1r[ib + 1], v.y, pa);
                pa = fmaf(w1r[ib + 2], v.z, pa); pa = fmaf(w1r[ib + 3], v.w, pa);
            }
            pa += __shfl_xor(pa, 1);
            pa += __shfl_xor(pa, 2);
            pa += __shfl_xor(pa, 4);
            if (o == 0) u2s[e_u] = K2 * pa;

            float zp = 0.0f;
            #pragma unroll
            for (int i4 = 0; i4 < 16; ++i4) {          // 2 addrs/bank: free
                const float4 v = sdc4[sz * 16 + i4];
                const int ib = i4 * 4;
                zp = fmaf(whr[ib + 0], v.x, zp); zp = fmaf(whr[ib + 1], v.y, zp);
                zp = fmaf(whr[ib + 2], v.z, zp); zp = fmaf(whr[ib + 3], v.w, zp);
            }
            zp += __shfl_xor(zp, 1);
            if (sz == 0) zs[jz] = zp;
            __syncthreads();                           // S1

            // ==== B: beta[tp] via 5-op tanh terms; y_tilde partial ====
            float pb = pinit;
            #pragma unroll
            for (int c4 = 0; c4 < 4; ++c4) {
                const float4 px = pX4[tp * S4 + p * 4 + c4];
                const float4 uu = u24[p * 4 + c4];
                const float4 ww = w24[p * 4 + c4];
                pb = fmaf(ww.x, RCP(EXP2(px.x + uu.x) + 1.0f), pb);
                pb = fmaf(ww.y, RCP(EXP2(px.y + uu.y) + 1.0f), pb);
                pb = fmaf(ww.z, RCP(EXP2(px.z + uu.z) + 1.0f), pb);
                pb = fmaf(ww.w, RCP(EXP2(px.w + uu.w) + 1.0f), pb);
            }
            pb += __shfl_xor(pb, 1);
            pb += __shfl_xor(pb, 2);
            pb += __shfl_xor(pb, 4);                   // pb = beta(tp), all lanes
            if (t == TM1 - 1 && p == 0) betas[tp] = pb;
            float prod = pb * XWfcs[tp];               // identical across p
            prod += __shfl_xor(prod, 8);
            prod += __shfl_xor(prod, 16);
            prod += __shfl_xor(prod, 32);              // sum over wave's 8 rows
            if ((tid & 63) == 0) swave[wv] = prod;
            __syncthreads();                           // S2

            // ==== C: y_tilde, z assembly, gates, state update (128 threads) ====
            if (tid < 128) {
                const float4 sa = sw4[0], sb = sw4[1], sc = sw4[2], sd = sw4[3];
                const float ssum = ((sa.x + sa.y) + (sa.z + sa.w))
                                 + ((sb.x + sb.y) + (sb.z + sb.w))
                                 + ((sc.x + sc.y) + (sc.z + sc.w))
                                 + ((sd.x + sd.y) + (sd.z + sd.w));
                const float ytl = fmaf(ys[t], wfcy, ssum + bfc_r);
                const int g = tid;
                const float zi = fmaf(ytl, wxbl[g],       wxbl[512 + g]) + zs[g];
                const float zf = fmaf(ytl, wxbl[128 + g], wxbl[640 + g]) + zs[128 + g];
                const float zg = fmaf(ytl, wxbl[256 + g], wxbl[768 + g]) + zs[256 + g];
                const float zo = fmaf(ytl, wxbl[384 + g], wxbl[896 + g]) + zs[384 + g];
                const float c_old = sdc[128 + g];
                const float cn = fast_sig(zf) * c_old + fast_sig(zi) * fast_tanh(zg);
                const float dn = fast_sig(zo) * fast_tanh(cn);
                sdc[g] = dn; sdc[128 + g] = cn;
            }
            __syncthreads();                           // S3
        }

        // ---- epilogue: final ctx + out = [d;ctx].Wf + bf ----
        if (tid < 128) {
            float cacc = 0.0f;
            for (int tq = 0; tq < TM1; ++tq)
                cacc = fmaf(betas[tq], Xs[tq * STRIDEF + tid], cacc);
            scrE[tid] = fmaf(sdc[tid], Wf[tid], cacc * Wf[128 + tid]);
        }
        __syncthreads();
        if (tid < 64) {
            float pp = scrE[tid] + scrE[tid + 64];
            #pragma unroll
            for (int off = 32; off > 0; off >>= 1) pp += __shfl_down(pp, off);
            if (tid == 0) out[b] = pp + bf_r;
        }
        __syncthreads();                               // protect Xs/sdc/betas
    }
}

extern "C" void kernel_launch(void* const* d_in, const int* in_sizes, int n_in,
                              void* d_out, int out_size, void* d_ws, size_t ws_size,
                              hipStream_t stream) {
    (void)in_sizes; (void)n_in; (void)d_ws; (void)ws_size; (void)out_size;
    const float* Xg    = (const float*)d_in[0];
    const float* yprev = (const float*)d_in[1];
    const float* W1    = (const float*)d_in[2];
    const float* b1    = (const float*)d_in[3];
    const float* W2    = (const float*)d_in[4];
    const float* b2    = (const float*)d_in[5];
    const float* Wfc   = (const float*)d_in[6];
    const float* bfc   = (const float*)d_in[7];
    const float* Wx    = (const float*)d_in[8];
    const float* Wh    = (const float*)d_in[9];
    const float* bl    = (const float*)d_in[10];
    const float* Wf    = (const float*)d_in[11];
    const float* bf    = (const float*)d_in[12];
    decoder_kernel<<<NB, NT, 0, stream>>>(
        Xg, yprev, W1, b1, W2, b2, Wfc, bfc, Wx, Wh, bl, Wf, bf, (float*)d_out);
}

// Round 4
// 3239.377 us; speedup vs baseline: 2.2911x; 2.2911x over previous
//
#include <hip/hip_runtime.h>
#include <hip/hip_fp16.h>

#define TM1   127
#define NE    128
#define NT    1024
#define NB    256
#define ROWH  136            // ushorts per preXh row: 2 halves x (64 data + 4 pad)
#define HALFH 68

#if __has_builtin(__builtin_amdgcn_exp2f)
#define EXP2(x) __builtin_amdgcn_exp2f(x)
#else
#define EXP2(x) exp2f(x)
#endif
#define RCP(x) __builtin_amdgcn_rcpf(x)
#define K2 2.885390081777927f   // 2*log2(e): tanh term = 1 - 2*rcp(exp2(K2*x)+1)

__device__ __forceinline__ float fast_sig(float x){ return RCP(1.0f + __expf(-x)); }
__device__ __forceinline__ float fast_tanh(float x){ float e = __expf(2.0f*x); return 1.0f - 2.0f*RCP(e+1.0f); }
__device__ __forceinline__ float blo(unsigned u){ union{unsigned i; float f;} v; v.i = u<<16;          return v.f; }
__device__ __forceinline__ float bhi(unsigned u){ union{unsigned i; float f;} v; v.i = u & 0xffff0000u; return v.f; }

// Pack W1dc (rows 0..255) and Wh into bf16 k-quads in workspace (re-done every launch).
__global__ void pack_weights(const float* __restrict__ W1, const float* __restrict__ Wh,
                             uint2* __restrict__ W1q, uint2* __restrict__ Whq) {
    const int t = blockIdx.x*256 + threadIdx.x;
    auto bf16 = [](float f)->unsigned {
        union{float f; unsigned u;} v; v.f = f;
        return (v.u + 0x7fffu + ((v.u>>16)&1u)) >> 16;   // RNE
    };
    if (t < 8192) {                       // W1q[k4][e], k4=0..63 covers k=0..255 ([d;c])
        const int k4 = t >> 7, e = t & 127;
        unsigned a = bf16(W1[(4*k4+0)*NE + e]);
        unsigned b = bf16(W1[(4*k4+1)*NE + e]);
        unsigned c = bf16(W1[(4*k4+2)*NE + e]);
        unsigned d = bf16(W1[(4*k4+3)*NE + e]);
        W1q[k4*128 + e] = make_uint2(a | (b<<16), c | (d<<16));
    } else if (t < 24576) {               // Whq[k4][j], k4=0..31 covers k=0..127
        const int t2 = t - 8192;
        const int k4 = t2 >> 9, j = t2 & 511;
        unsigned a = bf16(Wh[(4*k4+0)*512 + j]);
        unsigned b = bf16(Wh[(4*k4+1)*512 + j]);
        unsigned c = bf16(Wh[(4*k4+2)*512 + j]);
        unsigned d = bf16(Wh[(4*k4+3)*512 + j]);
        Whq[k4*512 + j] = make_uint2(a | (b<<16), c | (d<<16));
    }
}

__global__ __launch_bounds__(NT)
void decoder_kernel(const float* __restrict__ Xg,     // (1024,127,128)
                    const float* __restrict__ yprev,  // (1024,127)
                    const float* __restrict__ W1,     // (384,128)
                    const float* __restrict__ b1,
                    const float* __restrict__ W2,     // (128)
                    const float* __restrict__ b2v,
                    const float* __restrict__ Wfc,    // (129)
                    const float* __restrict__ bfcv,
                    const float* __restrict__ Wx,     // (512)
                    const float* __restrict__ blv,    // (512)
                    const float* __restrict__ Wf,     // (256)
                    const float* __restrict__ bfv,
                    const uint2* __restrict__ W1q,    // packed bf16 [64][128]
                    const uint2* __restrict__ Whq,    // packed bf16 [32][512]
                    float* __restrict__ out)          // (1024)
{
    __shared__ __align__(16) __half preXh[512 * ROWH];   // 139264 B: K2*(b1+X@W1x), fp16
    __shared__ __align__(16) float  sdc  [4 * 256];      // per batch: d(128) | c(128)
    __shared__ __align__(16) float  u2s  [4 * 128];      // K2*u
    __shared__ __align__(16) float  w2m2 [128];          // -2*W2
    __shared__ __align__(16) float  zsc  [4 * 512];      // d@Wh  (reused by epilogue)
    __shared__ __align__(16) float  XWfcs[4 * 128];
    __shared__ __align__(16) float  betas[4 * 128];
    __shared__ __align__(16) float  ys   [4 * 128];
    __shared__ float swv[16];

    const int tid = (int)threadIdx.x;
    const int b0  = (int)blockIdx.x * 4;
    // phase-role index sets
    const int eA = tid >> 3, oA = tid & 7;                 // A (+preamble preX): out e, 8-way k
    const int jC = tid >> 1, kh = tid & 1;                 // C: out column j, 2-way k
    const int bB = tid >> 8, tpB = (tid >> 1) & 127, hB = tid & 1;  // B: (batch,row,half)
    const int bG = tid >> 7, gG = tid & 127;               // gates
    const int wv = tid >> 6;

    const float wfcy  = Wfc[NE];
    const float bfc_r = bfcv[0];
    const float bf_r  = bfv[0];
    float wx0=0,wx1=0,wx2=0,wx3=0,bl0=0,bl1=0,bl2=0,bl3=0;
    if (tid < 512) {
        wx0 = Wx[gG];      wx1 = Wx[128+gG];  wx2 = Wx[256+gG];  wx3 = Wx[384+gG];
        bl0 = blv[gG];     bl1 = blv[128+gG]; bl2 = blv[256+gG]; bl3 = blv[384+gG];
    }
    // B-phase accumulator init: b2/2 + sum of my half's W2 (tanh = 1 - 2*rcp fold)
    float pinit = b2v[0] * 0.5f;
    for (int i = 0; i < 64; ++i) pinit += W2[hB*64 + i];

    if (tid < 128) w2m2[tid] = -2.0f * W2[tid];
    if (tid < 512) {
        const int b = tid >> 7, g = tid & 127;
        const float x00 = Xg[(size_t)(b0+b)*TM1*NE];       // d0=c0=X[b,0,0]
        sdc[b*256+g] = x00; sdc[b*256+128+g] = x00;
        betas[tid] = 0.0f;
        if (g < TM1) ys[b*128+g] = yprev[(size_t)(b0+b)*TM1 + g];
        float xw = 0.0f;                                   // XWfc[t'] = X[t'].Wfc[:128]
        if (g < TM1) {
            const float4* xr = (const float4*)(Xg + ((size_t)(b0+b)*TM1 + g)*NE);
            #pragma unroll 4
            for (int i = 0; i < 32; ++i) {
                const float4 x = xr[i];
                const float4 w = *(const float4*)&Wfc[i*4];
                xw = fmaf(x.x,w.x, fmaf(x.y,w.y, fmaf(x.z,w.z, fmaf(x.w,w.w, xw))));
            }
        }
        XWfcs[tid] = xw;                                   // row 127 -> 0
    }
    if (tid < 544) {                                       // zero preXh pad rows (tp=127)
        const int bb = tid / 136, mm = tid - bb*136;
        preXh[(bb*128 + 127)*ROWH + mm] = __float2half(0.0f);
    }

    // ---- preamble: preX (fp16, K2-scaled) ----
    {
        float w1x[16];
        const float b1r = b1[eA];
        #pragma unroll
        for (int i = 0; i < 16; ++i) w1x[i] = W1[(256 + oA*16 + i)*NE + eA];
        for (int b = 0; b < 4; ++b) {
            const float* Xbase = Xg + (size_t)(b0+b)*TM1*NE;
            for (int tp = 0; tp < TM1; ++tp) {
                const float4* xr = (const float4*)(Xbase + tp*NE + oA*16);
                float s = 0.0f;
                #pragma unroll
                for (int q = 0; q < 4; ++q) {
                    const float4 x = xr[q];
                    s = fmaf(w1x[q*4+0],x.x, fmaf(w1x[q*4+1],x.y,
                        fmaf(w1x[q*4+2],x.z, fmaf(w1x[q*4+3],x.w, s))));
                }
                s += __shfl_xor(s,1); s += __shfl_xor(s,2); s += __shfl_xor(s,4);
                if (oA == 0)
                    preXh[(b*128+tp)*ROWH + (eA>>6)*HALFH + (eA&63)] =
                        __float2half(K2 * (s + b1r));
            }
        }
    }
    __syncthreads();

    for (int t = 0; t < TM1; ++t) {
        // ==== A: u[b][e] partials, 8-way k-split (rotated k4 -> conflict-free) ====
        {
            float a0=0.f,a1=0.f,a2=0.f,a3=0.f;
            #pragma unroll
            for (int i = 0; i < 8; ++i) {
                const int k4 = oA*8 + ((i + oA) & 7);
                const uint2 w = W1q[k4*128 + eA];
                const float wa=blo(w.x), wb=bhi(w.x), wc=blo(w.y), wd=bhi(w.y);
                const float4 v0 = *(const float4*)&sdc[        k4*4];
                const float4 v1 = *(const float4*)&sdc[ 256 +  k4*4];
                const float4 v2 = *(const float4*)&sdc[ 512 +  k4*4];
                const float4 v3 = *(const float4*)&sdc[ 768 +  k4*4];
                a0 = fmaf(wa,v0.x,fmaf(wb,v0.y,fmaf(wc,v0.z,fmaf(wd,v0.w,a0))));
                a1 = fmaf(wa,v1.x,fmaf(wb,v1.y,fmaf(wc,v1.z,fmaf(wd,v1.w,a1))));
                a2 = fmaf(wa,v2.x,fmaf(wb,v2.y,fmaf(wc,v2.z,fmaf(wd,v2.w,a2))));
                a3 = fmaf(wa,v3.x,fmaf(wb,v3.y,fmaf(wc,v3.z,fmaf(wd,v3.w,a3))));
            }
            a0 += __shfl_xor(a0,1); a0 += __shfl_xor(a0,2); a0 += __shfl_xor(a0,4);
            a1 += __shfl_xor(a1,1); a1 += __shfl_xor(a1,2); a1 += __shfl_xor(a1,4);
            a2 += __shfl_xor(a2,1); a2 += __shfl_xor(a2,2); a2 += __shfl_xor(a2,4);
            a3 += __shfl_xor(a3,1); a3 += __shfl_xor(a3,2); a3 += __shfl_xor(a3,4);
            if (oA == 0) {
                u2s[      eA] = K2*a0; u2s[128 + eA] = K2*a1;
                u2s[256 + eA] = K2*a2; u2s[384 + eA] = K2*a3;
            }
        }
        // ==== C: z[b][j] = d@Wh partials, 2-way k-split ====
        {
            float z0=0.f,z1=0.f,z2=0.f,z3=0.f;
            #pragma unroll
            for (int i = 0; i < 16; ++i) {
                const int k4 = kh*16 + i;                  // k4<32 -> d only
                const uint2 w = Whq[k4*512 + jC];
                const float wa=blo(w.x), wb=bhi(w.x), wc=blo(w.y), wd=bhi(w.y);
                const float4 v0 = *(const float4*)&sdc[        k4*4];
                const float4 v1 = *(const float4*)&sdc[ 256 +  k4*4];
                const float4 v2 = *(const float4*)&sdc[ 512 +  k4*4];
                const float4 v3 = *(const float4*)&sdc[ 768 +  k4*4];
                z0 = fmaf(wa,v0.x,fmaf(wb,v0.y,fmaf(wc,v0.z,fmaf(wd,v0.w,z0))));
                z1 = fmaf(wa,v1.x,fmaf(wb,v1.y,fmaf(wc,v1.z,fmaf(wd,v1.w,z1))));
                z2 = fmaf(wa,v2.x,fmaf(wb,v2.y,fmaf(wc,v2.z,fmaf(wd,v2.w,z2))));
                z3 = fmaf(wa,v3.x,fmaf(wb,v3.y,fmaf(wc,v3.z,fmaf(wd,v3.w,z3))));
            }
            z0 += __shfl_xor(z0,1); z1 += __shfl_xor(z1,1);
            z2 += __shfl_xor(z2,1); z3 += __shfl_xor(z3,1);
            if (kh == 0) {
                zsc[       jC] = z0; zsc[ 512 + jC] = z1;
                zsc[1024 + jC] = z2; zsc[1536 + jC] = z3;
            }
        }
        __syncthreads();                                   // S1

        // ==== B: beta[b][tp] (half-row per thread, 5-op tanh terms) ====
        float pbK;
        {
            const __half2* ph  = (const __half2*)(preXh + (bB*128+tpB)*ROWH + hB*HALFH);
            const float2*  uf  = (const float2*)(u2s  + bB*128 + hB*64);
            const float2*  wf2 = (const float2*)(w2m2 + hB*64);
            float p0 = pinit, p1 = 0.0f;
            #pragma unroll
            for (int i = 0; i < 32; ++i) {
                const __half2 h2 = ph[i];
                const float2  uu = uf[i];
                const float2  ww = wf2[i];
                p0 = fmaf(ww.x, RCP(EXP2(__low2float (h2) + uu.x) + 1.0f), p0);
                p1 = fmaf(ww.y, RCP(EXP2(__high2float(h2) + uu.y) + 1.0f), p1);
            }
            float pb = p0 + p1;
            pb += __shfl_xor(pb, 1);                       // full row sum
            pbK = pb;
            float prod = pb * XWfcs[bB*128 + tpB];         // row 127 -> *0
            prod += __shfl_xor(prod, 2);  prod += __shfl_xor(prod, 4);
            prod += __shfl_xor(prod, 8);  prod += __shfl_xor(prod, 16);
            prod += __shfl_xor(prod, 32);                  // wave's 32 rows (no xor1: halves dup)
            if ((tid & 63) == 0) swv[wv] = prod;
        }
        if (t == TM1-1 && hB == 0 && tpB < TM1) betas[bB*128 + tpB] = pbK;
        __syncthreads();                                   // S2

        // ==== gates ====
        if (tid < 512) {
            const float ssum = swv[bG*4] + swv[bG*4+1] + swv[bG*4+2] + swv[bG*4+3];
            const float ytl  = fmaf(ys[bG*128 + t], wfcy, ssum + bfc_r);
            const float zi = fmaf(ytl,wx0,bl0) + zsc[bG*512 +       gG];
            const float zf = fmaf(ytl,wx1,bl1) + zsc[bG*512 + 128 + gG];
            const float zg = fmaf(ytl,wx2,bl2) + zsc[bG*512 + 256 + gG];
            const float zo = fmaf(ytl,wx3,bl3) + zsc[bG*512 + 384 + gG];
            const float c_old = sdc[bG*256 + 128 + gG];
            const float cn = fast_sig(zf)*c_old + fast_sig(zi)*fast_tanh(zg);
            const float dn = fast_sig(zo)*fast_tanh(cn);
            sdc[bG*256 + gG] = dn; sdc[bG*256 + 128 + gG] = cn;
        }
        __syncthreads();                                   // S3
    }

    // ---- epilogue: final ctx from betas + global X, then out ----
    if (tid < 512) {
        const int b = tid >> 7, e = tid & 127;
        const float* Xb = Xg + (size_t)(b0+b)*TM1*NE + e;
        float cacc = 0.0f;
        #pragma unroll 4
        for (int tp = 0; tp < TM1; ++tp)
            cacc = fmaf(betas[b*128 + tp], Xb[(size_t)tp*NE], cacc);
        zsc[tid] = fmaf(sdc[b*256 + e], Wf[e], cacc * Wf[128 + e]);
    }
    __syncthreads();
    if (tid < 4) {
        float s = 0.0f;
        for (int i = 0; i < 128; ++i) s += zsc[tid*128 + i];
        out[b0 + tid] = s + bf_r;
    }
}

extern "C" void kernel_launch(void* const* d_in, const int* in_sizes, int n_in,
                              void* d_out, int out_size, void* d_ws, size_t ws_size,
                              hipStream_t stream) {
    (void)in_sizes; (void)n_in; (void)ws_size; (void)out_size;
    const float* Xg    = (const float*)d_in[0];
    const float* yprev = (const float*)d_in[1];
    const float* W1    = (const float*)d_in[2];
    const float* b1    = (const float*)d_in[3];
    const float* W2    = (const float*)d_in[4];
    const float* b2    = (const float*)d_in[5];
    const float* Wfc   = (const float*)d_in[6];
    const float* bfc   = (const float*)d_in[7];
    const float* Wx    = (const float*)d_in[8];
    const float* Wh    = (const float*)d_in[9];
    const float* bl    = (const float*)d_in[10];
    const float* Wf    = (const float*)d_in[11];
    const float* bf    = (const float*)d_in[12];

    uint2* W1q = (uint2*)d_ws;                         // 64 KB
    uint2* Whq = (uint2*)((char*)d_ws + 65536);        // 128 KB

    pack_weights<<<96, 256, 0, stream>>>(W1, Wh, W1q, Whq);
    decoder_kernel<<<NB, NT, 0, stream>>>(
        Xg, yprev, W1, b1, W2, b2, Wfc, bfc, Wx, bl, Wf, bf, W1q, Whq, (float*)d_out);
}

// Round 5
// 2165.405 us; speedup vs baseline: 3.4274x; 1.4960x over previous
//
#include <hip/hip_runtime.h>
#include <hip/hip_fp16.h>

#define TM1   127
#define NE    128
#define NT    1024
#define NB    256
#define ROWH  132            // ushorts per preXh row (264 B): bank = 2r+h+i -> exactly 2-way, free
#define HALFH 66             // ushorts per half-row (64 data + 2 pad); 132 B offset keeps 4B align

#if __has_builtin(__builtin_amdgcn_exp2f)
#define EXP2(x) __builtin_amdgcn_exp2f(x)
#else
#define EXP2(x) exp2f(x)
#endif
#define RCP(x) __builtin_amdgcn_rcpf(x)
#define K2 2.885390081777927f   // 2*log2(e): tanh term = 1 - 2*rcp(exp2(K2*x)+1)

__device__ __forceinline__ float fast_sig(float x){ return RCP(1.0f + __expf(-x)); }
__device__ __forceinline__ float fast_tanh(float x){ float e = __expf(2.0f*x); return 1.0f - 2.0f*RCP(e+1.0f); }
__device__ __forceinline__ float blo(unsigned u){ union{unsigned i; float f;} v; v.i = u<<16;          return v.f; }
__device__ __forceinline__ float bhi(unsigned u){ union{unsigned i; float f;} v; v.i = u & 0xffff0000u; return v.f; }

// Pack W1dc (rows 0..255) and Wh into bf16 k-quads in workspace (same work every launch).
__global__ void pack_weights(const float* __restrict__ W1, const float* __restrict__ Wh,
                             uint2* __restrict__ W1q, uint2* __restrict__ Whq) {
    const int t = blockIdx.x*256 + threadIdx.x;
    auto bf16 = [](float f)->unsigned {
        union{float f; unsigned u;} v; v.f = f;
        return (v.u + 0x7fffu + ((v.u>>16)&1u)) >> 16;   // RNE
    };
    if (t < 8192) {                       // W1q[k4][e], k4=0..63 covers k=0..255 ([d;c])
        const int k4 = t >> 7, e = t & 127;
        unsigned a = bf16(W1[(4*k4+0)*NE + e]);
        unsigned b = bf16(W1[(4*k4+1)*NE + e]);
        unsigned c = bf16(W1[(4*k4+2)*NE + e]);
        unsigned d = bf16(W1[(4*k4+3)*NE + e]);
        W1q[k4*128 + e] = make_uint2(a | (b<<16), c | (d<<16));
    } else if (t < 24576) {               // Whq[k4][j], k4=0..31 covers k=0..127
        const int t2 = t - 8192;
        const int k4 = t2 >> 9, j = t2 & 511;
        unsigned a = bf16(Wh[(4*k4+0)*512 + j]);
        unsigned b = bf16(Wh[(4*k4+1)*512 + j]);
        unsigned c = bf16(Wh[(4*k4+2)*512 + j]);
        unsigned d = bf16(Wh[(4*k4+3)*512 + j]);
        Whq[k4*512 + j] = make_uint2(a | (b<<16), c | (d<<16));
    }
}

__global__ __launch_bounds__(NT)
void decoder_kernel(const float* __restrict__ Xg,     // (1024,127,128)
                    const float* __restrict__ yprev,  // (1024,127)
                    const float* __restrict__ W1,     // (384,128)
                    const float* __restrict__ b1,
                    const float* __restrict__ W2,     // (128)
                    const float* __restrict__ b2v,
                    const float* __restrict__ Wfc,    // (129)
                    const float* __restrict__ bfcv,
                    const float* __restrict__ Wx,     // (512)
                    const float* __restrict__ blv,    // (512)
                    const float* __restrict__ Wf,     // (256)
                    const float* __restrict__ bfv,
                    const uint2* __restrict__ W1q,    // packed bf16 [64][128]
                    const uint2* __restrict__ Whq,    // packed bf16 [32][512]
                    float* __restrict__ out)          // (1024)
{
    __shared__ __align__(16) __half  preXh[512 * ROWH];  // 135168 B: K2*(b1+X@W1x), fp16
    __shared__ __align__(16) float   sdc  [1024];        // per batch: d(128) | c(128)
    __shared__ __align__(16) float2  uws  [512];         // per (b,e): (K2*u, -2*W2)
    __shared__ __align__(16) float   w2m2 [128];
    __shared__ __align__(16) float   zsc  [2048];        // d@Wh (reused by epilogue)
    __shared__ __align__(16) float   XWfcs[512];
    __shared__ __align__(16) float   betas[512];
    __shared__ __align__(16) float   ys   [512];
    __shared__ __align__(16) float   wxbl [1024];        // [g*8+q]=Wx[q*128+g], [g*8+4+q]=bl
    __shared__ __align__(16) float   params[8];          // 0:wfcy 1:bfc 2:bf 3:pinit0 4:pinit1
    __shared__ float swv[16];

    const int tid = (int)threadIdx.x;
    const int b0  = (int)blockIdx.x * 4;
    const int eA = tid >> 3, oA = tid & 7;                 // A/preamble: out e, 8-way k
    const int jC = tid >> 1, kh = tid & 1;                 // C: out column j, 2-way k
    const int bB = tid >> 8, tpB = (tid >> 1) & 127, hB = tid & 1;  // B: (batch,row,half)
    const int bG = tid >> 7, gG = tid & 127;               // gates
    const int wv = tid >> 6;

    // ---- init (no loop-persistent VGPR state anywhere) ----
    if (tid < 128) w2m2[tid] = -2.0f * W2[tid];
    if (tid == 0) { params[0] = Wfc[NE]; params[1] = bfcv[0]; params[2] = bfv[0]; }
    if (tid == 4 || tid == 5) {                            // pinit[h] = b2/2 + sum W2[h-half]
        const int h = tid - 4;
        float s = b2v[0] * 0.5f;
        for (int i = 0; i < 64; ++i) s += W2[h*64 + i];
        params[3 + h] = s;
    }
    if (tid < 512) {
        const int b = tid >> 7, g = tid & 127;
        const float x00 = Xg[(size_t)(b0+b)*TM1*NE];       // d0=c0=X[b,0,0]
        sdc[b*256 + g] = x00; sdc[b*256 + 128 + g] = x00;
        betas[tid] = 0.0f;
        ys[tid] = (g < TM1) ? yprev[(size_t)(b0+b)*TM1 + g] : 0.0f;
        wxbl[g*8 + b]     = Wx [b*128 + g];
        wxbl[g*8 + 4 + b] = blv[b*128 + g];
        float xw = 0.0f;                                   // XWfc[t'] = X[t'].Wfc[:128]
        if (g < TM1) {
            const float4* xr = (const float4*)(Xg + ((size_t)(b0+b)*TM1 + g)*NE);
            #pragma unroll 4
            for (int i = 0; i < 32; ++i) {
                const float4 x = xr[i];
                const float4 w = *(const float4*)&Wfc[i*4];
                xw = fmaf(x.x,w.x, fmaf(x.y,w.y, fmaf(x.z,w.z, fmaf(x.w,w.w, xw))));
            }
        }
        XWfcs[tid] = xw;                                   // row 127 -> 0
    }
    if (tid < 528) {                                       // zero pad row (tp=127) per batch
        const int bb = tid / 132, mm = tid - bb*132;
        preXh[(bb*128 + 127)*ROWH + mm] = __float2half(0.0f);
    }

    // ---- preamble: preX (fp16, K2-scaled) ----
    {
        float w1x[16];
        const float b1r = b1[eA];
        #pragma unroll
        for (int i = 0; i < 16; ++i) w1x[i] = W1[(256 + oA*16 + i)*NE + eA];
        for (int b = 0; b < 4; ++b) {
            const float* Xbase = Xg + (size_t)(b0+b)*TM1*NE;
            for (int tp = 0; tp < TM1; ++tp) {
                const float4* xr = (const float4*)(Xbase + tp*NE + oA*16);
                float s = 0.0f;
                #pragma unroll
                for (int q = 0; q < 4; ++q) {
                    const float4 x = xr[q];
                    s = fmaf(w1x[q*4+0],x.x, fmaf(w1x[q*4+1],x.y,
                        fmaf(w1x[q*4+2],x.z, fmaf(w1x[q*4+3],x.w, s))));
                }
                s += __shfl_xor(s,1); s += __shfl_xor(s,2); s += __shfl_xor(s,4);
                if (oA == 0)
                    preXh[(b*128+tp)*ROWH + (eA>>6)*HALFH + (eA&63)] =
                        __float2half(K2 * (s + b1r));
            }
        }
    }
    __syncthreads();

    for (int t = 0; t < TM1; ++t) {
        // ==== A: u[b][e] partials, 8-way k-split (rotated k4 -> conflict-free) ====
        {
            float a0=0.f,a1=0.f,a2=0.f,a3=0.f;
            #pragma unroll 4
            for (int i = 0; i < 8; ++i) {
                const int k4 = oA*8 + ((i + oA) & 7);
                const uint2 w = W1q[k4*128 + eA];
                const float wa=blo(w.x), wb=bhi(w.x), wc=blo(w.y), wd=bhi(w.y);
                const float4 v0 = *(const float4*)&sdc[        k4*4];
                const float4 v1 = *(const float4*)&sdc[ 256 +  k4*4];
                const float4 v2 = *(const float4*)&sdc[ 512 +  k4*4];
                const float4 v3 = *(const float4*)&sdc[ 768 +  k4*4];
                a0 = fmaf(wa,v0.x,fmaf(wb,v0.y,fmaf(wc,v0.z,fmaf(wd,v0.w,a0))));
                a1 = fmaf(wa,v1.x,fmaf(wb,v1.y,fmaf(wc,v1.z,fmaf(wd,v1.w,a1))));
                a2 = fmaf(wa,v2.x,fmaf(wb,v2.y,fmaf(wc,v2.z,fmaf(wd,v2.w,a2))));
                a3 = fmaf(wa,v3.x,fmaf(wb,v3.y,fmaf(wc,v3.z,fmaf(wd,v3.w,a3))));
            }
            a0 += __shfl_xor(a0,1); a0 += __shfl_xor(a0,2); a0 += __shfl_xor(a0,4);
            a1 += __shfl_xor(a1,1); a1 += __shfl_xor(a1,2); a1 += __shfl_xor(a1,4);
            a2 += __shfl_xor(a2,1); a2 += __shfl_xor(a2,2); a2 += __shfl_xor(a2,4);
            a3 += __shfl_xor(a3,1); a3 += __shfl_xor(a3,2); a3 += __shfl_xor(a3,4);
            if (oA == 0) {
                const float w2e = w2m2[eA];
                uws[      eA] = make_float2(K2*a0, w2e);
                uws[128 + eA] = make_float2(K2*a1, w2e);
                uws[256 + eA] = make_float2(K2*a2, w2e);
                uws[384 + eA] = make_float2(K2*a3, w2e);
            }
        }
        // ==== C: z[b][j] = d@Wh partials, 2-way k-split ====
        {
            float z0=0.f,z1=0.f,z2=0.f,z3=0.f;
            #pragma unroll 4
            for (int i = 0; i < 16; ++i) {
                const int k4 = kh*16 + i;                  // k4<32 -> d only
                const uint2 w = Whq[k4*512 + jC];
                const float wa=blo(w.x), wb=bhi(w.x), wc=blo(w.y), wd=bhi(w.y);
                const float4 v0 = *(const float4*)&sdc[        k4*4];
                const float4 v1 = *(const float4*)&sdc[ 256 +  k4*4];
                const float4 v2 = *(const float4*)&sdc[ 512 +  k4*4];
                const float4 v3 = *(const float4*)&sdc[ 768 +  k4*4];
                z0 = fmaf(wa,v0.x,fmaf(wb,v0.y,fmaf(wc,v0.z,fmaf(wd,v0.w,z0))));
                z1 = fmaf(wa,v1.x,fmaf(wb,v1.y,fmaf(wc,v1.z,fmaf(wd,v1.w,z1))));
                z2 = fmaf(wa,v2.x,fmaf(wb,v2.y,fmaf(wc,v2.z,fmaf(wd,v2.w,z2))));
                z3 = fmaf(wa,v3.x,fmaf(wb,v3.y,fmaf(wc,v3.z,fmaf(wd,v3.w,z3))));
            }
            z0 += __shfl_xor(z0,1); z1 += __shfl_xor(z1,1);
            z2 += __shfl_xor(z2,1); z3 += __shfl_xor(z3,1);
            if (kh == 0) {
                zsc[       jC] = z0; zsc[ 512 + jC] = z1;
                zsc[1024 + jC] = z2; zsc[1536 + jC] = z3;
            }
        }
        __syncthreads();                                   // S1

        // ==== B: beta[b][tp] (half-row per thread, fused (u,-2W2) b128 reads) ====
        {
            const __half2* ph  = (const __half2*)(preXh + (bB*128+tpB)*ROWH + hB*HALFH);
            const float4*  uw4 = (const float4*)(uws + bB*128 + hB*64);
            float p0 = params[3 + hB], p1 = 0.0f;
            #pragma unroll 8
            for (int i = 0; i < 32; ++i) {
                const __half2 h2 = ph[i];
                const float4  uw = uw4[i];                 // (u0,w0,u1,w1)
                p0 = fmaf(uw.y, RCP(EXP2(__low2float (h2) + uw.x) + 1.0f), p0);
                p1 = fmaf(uw.w, RCP(EXP2(__high2float(h2) + uw.z) + 1.0f), p1);
            }
            float pb = p0 + p1;
            pb += __shfl_xor(pb, 1);                       // full row sum
            if (t == TM1-1 && hB == 0 && tpB < TM1) betas[bB*128 + tpB] = pb;
            float prod = pb * XWfcs[bB*128 + tpB];         // row 127 -> *0
            prod += __shfl_xor(prod, 2);  prod += __shfl_xor(prod, 4);
            prod += __shfl_xor(prod, 8);  prod += __shfl_xor(prod, 16);
            prod += __shfl_xor(prod, 32);                  // wave's 32 rows (halves dup)
            if ((tid & 63) == 0) swv[wv] = prod;
        }
        __syncthreads();                                   // S2

        // ==== gates ====
        if (tid < 512) {
            const float ssum = swv[bG*4] + swv[bG*4+1] + swv[bG*4+2] + swv[bG*4+3];
            const float ytl  = fmaf(ys[bG*128 + t], params[0], ssum + params[1]);
            const float4 wxv = *(const float4*)&wxbl[gG*8];
            const float4 bl4 = *(const float4*)&wxbl[gG*8 + 4];
            const float zi = fmaf(ytl,wxv.x,bl4.x) + zsc[bG*512 +       gG];
            const float zf = fmaf(ytl,wxv.y,bl4.y) + zsc[bG*512 + 128 + gG];
            const float zg = fmaf(ytl,wxv.z,bl4.z) + zsc[bG*512 + 256 + gG];
            const float zo = fmaf(ytl,wxv.w,bl4.w) + zsc[bG*512 + 384 + gG];
            const float c_old = sdc[bG*256 + 128 + gG];
            const float cn = fast_sig(zf)*c_old + fast_sig(zi)*fast_tanh(zg);
            const float dn = fast_sig(zo)*fast_tanh(cn);
            sdc[bG*256 + gG] = dn; sdc[bG*256 + 128 + gG] = cn;
        }
        __syncthreads();                                   // S3
    }

    // ---- epilogue: final ctx from betas + global X, then out ----
    if (tid < 512) {
        const int b = tid >> 7, e = tid & 127;
        const float* Xb = Xg + (size_t)(b0+b)*TM1*NE + e;
        float cacc = 0.0f;
        #pragma unroll 4
        for (int tp = 0; tp < TM1; ++tp)
            cacc = fmaf(betas[b*128 + tp], Xb[(size_t)tp*NE], cacc);
        zsc[tid] = fmaf(sdc[b*256 + e], Wf[e], cacc * Wf[128 + e]);
    }
    __syncthreads();
    if (tid < 4) {
        float s = 0.0f;
        for (int i = 0; i < 128; ++i) s += zsc[tid*128 + i];
        out[b0 + tid] = s + params[2];
    }
}

extern "C" void kernel_launch(void* const* d_in, const int* in_sizes, int n_in,
                              void* d_out, int out_size, void* d_ws, size_t ws_size,
                              hipStream_t stream) {
    (void)in_sizes; (void)n_in; (void)ws_size; (void)out_size;
    const float* Xg    = (const float*)d_in[0];
    const float* yprev = (const float*)d_in[1];
    const float* W1    = (const float*)d_in[2];
    const float* b1    = (const float*)d_in[3];
    const float* W2    = (const float*)d_in[4];
    const float* b2    = (const float*)d_in[5];
    const float* Wfc   = (const float*)d_in[6];
    const float* bfc   = (const float*)d_in[7];
    const float* Wx    = (const float*)d_in[8];
    const float* Wh    = (const float*)d_in[9];
    const float* bl    = (const float*)d_in[10];
    const float* Wf    = (const float*)d_in[11];
    const float* bf    = (const float*)d_in[12];

    uint2* W1q = (uint2*)d_ws;                         // 64 KB
    uint2* Whq = (uint2*)((char*)d_ws + 65536);        // 128 KB

    pack_weights<<<96, 256, 0, stream>>>(W1, Wh, W1q, Whq);
    decoder_kernel<<<NB, NT, 0, stream>>>(
        Xg, yprev, W1, b1, W2, b2, Wfc, bfc, Wx, bl, Wf, bf, W1q, Whq, (float*)d_out);
}